// Round 1
// baseline (316.162 us; speedup 1.0000x reference)
//
#include <hip/hip_runtime.h>

#define IMG_H 512
#define IMG_W 512
#define NIMG 96            // B*C
#define WOUT 506
#define STRIP 23
#define NSTRIPS 22         // 22*23 = 506
#define TOTAL_VALS 24579456.0f   // 96 * 506 * 506

__device__ __forceinline__ unsigned fkey(float f){
    unsigned b = __float_as_uint(f);
    return (b & 0x80000000u) ? ~b : (b | 0x80000000u);
}
__device__ __forceinline__ float fdec(unsigned k){
    unsigned b = (k & 0x80000000u) ? (k ^ 0x80000000u) : ~k;
    return __uint_as_float(b);
}

// ---------------- kernel 1: per-batch-image min/max of img2 ----------------
__global__ __launch_bounds__(256) void minmax_kernel(const float4* __restrict__ y4,
                                                     unsigned* __restrict__ maxk,
                                                     unsigned* __restrict__ mink){
    int blk  = blockIdx.x;          // 256 blocks = 32 images * 8 chunks
    int img  = blk >> 3;            // batch index 0..31
    int chnk = blk & 7;
    const float4* base = y4 + (size_t)img * (786432/4) + (size_t)chnk * 24576;
    float mn = 3.4e38f, mx = -3.4e38f;
    for (int i = threadIdx.x; i < 24576; i += 256){
        float4 v = base[i];
        mn = fminf(mn, fminf(fminf(v.x, v.y), fminf(v.z, v.w)));
        mx = fmaxf(mx, fmaxf(fmaxf(v.x, v.y), fmaxf(v.z, v.w)));
    }
    #pragma unroll
    for (int off = 32; off; off >>= 1){
        mn = fminf(mn, __shfl_down(mn, off));
        mx = fmaxf(mx, __shfl_down(mx, off));
    }
    if ((threadIdx.x & 63) == 0){
        atomicMax(&maxk[img], fkey(mx));
        atomicMin(&mink[img], fkey(mn));
    }
}

// ---------------- kernel 2: SSIM map + accumulate ----------------
// One wave (64 threads) per block. Thread t owns input columns [8t, 8t+8).
// Vertical 7-row sliding sums in registers; horizontal 7-col sums via LDS.

#define ROWOP(row, OPA) { \
    const float* xr = x + (size_t)(row)*IMG_W + c0; \
    const float* yr = y + (size_t)(row)*IMG_W + c0; \
    float4 xa = *(const float4*)xr;     float4 xb = *(const float4*)(xr+4); \
    float4 ya = *(const float4*)yr;     float4 yb = *(const float4*)(yr+4); \
    float xv[8] = {xa.x,xa.y,xa.z,xa.w,xb.x,xb.y,xb.z,xb.w}; \
    float yv[8] = {ya.x,ya.y,ya.z,ya.w,yb.x,yb.y,yb.z,yb.w}; \
    _Pragma("unroll") \
    for (int k = 0; k < 8; k++){ \
        sx[k]  OPA xv[k]; \
        sy[k]  OPA yv[k]; \
        sxx[k] OPA xv[k]*xv[k]; \
        syy[k] OPA yv[k]*yv[k]; \
        sxy[k] OPA xv[k]*yv[k]; \
    } }

#define HWIN(q, outw) { \
    float4 ha = *(float4*)&cs[q][c0];    float4 hb = *(float4*)&cs[q][c0+4]; \
    float4 hc = *(float4*)&cs[q][c0+8];  float4 hd = *(float4*)&cs[q][c0+12]; \
    float h[16] = {ha.x,ha.y,ha.z,ha.w, hb.x,hb.y,hb.z,hb.w, \
                   hc.x,hc.y,hc.z,hc.w, hd.x,hd.y,hd.z,hd.w}; \
    float w = h[0]+h[1]+h[2]+h[3]+h[4]+h[5]+h[6]; \
    outw[0] = w; \
    _Pragma("unroll") \
    for (int j = 1; j < 8; j++){ w += h[j+6] - h[j-1]; outw[j] = w; } }

__global__ __launch_bounds__(64) void ssim_kernel(const float* __restrict__ img1,
                                                  const float* __restrict__ img2,
                                                  const unsigned* __restrict__ maxk,
                                                  const unsigned* __restrict__ mink,
                                                  float* __restrict__ acc){
    __shared__ float cs[5][520];

    int img   = blockIdx.x % NIMG;
    int strip = blockIdx.x / NIMG;
    int b     = img / 3;

    float dr = fdec(maxk[b]) - fdec(mink[b]);
    float c1 = 0.01f * dr;  c1 *= c1;
    float c2 = 0.03f * dr;  c2 *= c2;

    const float* x = img1 + (size_t)img * (IMG_H*IMG_W);
    const float* y = img2 + (size_t)img * (IMG_H*IMG_W);

    int t  = threadIdx.x;
    int c0 = t * 8;

    float sx[8]={0,0,0,0,0,0,0,0}, sy[8]={0,0,0,0,0,0,0,0};
    float sxx[8]={0,0,0,0,0,0,0,0}, syy[8]={0,0,0,0,0,0,0,0}, sxy[8]={0,0,0,0,0,0,0,0};

    int r0 = strip * STRIP;

    // init vertical sums over input rows [r0, r0+7)
    for (int rr = 0; rr < 7; rr++){ ROWOP(r0+rr, +=) }

    float accS = 0.0f;

    for (int r = r0; r < r0 + STRIP; r++){
        // publish column sums
        *(float4*)&cs[0][c0]   = make_float4(sx[0],sx[1],sx[2],sx[3]);
        *(float4*)&cs[0][c0+4] = make_float4(sx[4],sx[5],sx[6],sx[7]);
        *(float4*)&cs[1][c0]   = make_float4(sy[0],sy[1],sy[2],sy[3]);
        *(float4*)&cs[1][c0+4] = make_float4(sy[4],sy[5],sy[6],sy[7]);
        *(float4*)&cs[2][c0]   = make_float4(sxx[0],sxx[1],sxx[2],sxx[3]);
        *(float4*)&cs[2][c0+4] = make_float4(sxx[4],sxx[5],sxx[6],sxx[7]);
        *(float4*)&cs[3][c0]   = make_float4(syy[0],syy[1],syy[2],syy[3]);
        *(float4*)&cs[3][c0+4] = make_float4(syy[4],syy[5],syy[6],syy[7]);
        *(float4*)&cs[4][c0]   = make_float4(sxy[0],sxy[1],sxy[2],sxy[3]);
        *(float4*)&cs[4][c0+4] = make_float4(sxy[4],sxy[5],sxy[6],sxy[7]);
        __syncthreads();

        float wsx[8], wsy[8], wsxx[8], wsyy[8], wsxy[8];
        HWIN(0, wsx)  HWIN(1, wsy)  HWIN(2, wsxx)  HWIN(3, wsyy)  HWIN(4, wsxy)
        __syncthreads();   // before next row overwrites cs

        const float inv  = 1.0f/49.0f;
        const float covn = 49.0f/48.0f;
        #pragma unroll
        for (int j = 0; j < 8; j++){
            if (c0 + j < WOUT){
                float ux  = wsx[j]*inv,  uy  = wsy[j]*inv;
                float exx = wsxx[j]*inv, eyy = wsyy[j]*inv, exy = wsxy[j]*inv;
                float vx  = covn*(exx - ux*ux);
                float vy  = covn*(eyy - uy*uy);
                float vxy = covn*(exy - ux*uy);
                float a1 = 2.0f*ux*uy + c1,        a2 = 2.0f*vxy + c2;
                float b1 = ux*ux + uy*uy + c1,     b2 = vx + vy + c2;
                accS += (a1*a2) / (b1*b2);
            }
        }

        if (r < r0 + STRIP - 1){
            ROWOP(r+7, +=)   // entering row
            ROWOP(r,   -=)   // leaving row (L1-resident reload)
        }
    }

    #pragma unroll
    for (int off = 32; off; off >>= 1)
        accS += __shfl_down(accS, off);
    if (t == 0)
        atomicAdd(acc, accS);
}

// ---------------- kernel 3: finalize ----------------
__global__ void finalize_kernel(const float* __restrict__ acc, float* __restrict__ out){
    out[0] = 1.0f - acc[0] * (1.0f / TOTAL_VALS);
}

extern "C" void kernel_launch(void* const* d_in, const int* in_sizes, int n_in,
                              void* d_out, int out_size, void* d_ws, size_t ws_size,
                              hipStream_t stream) {
    const float* img1 = (const float*)d_in[0];
    const float* img2 = (const float*)d_in[1];
    float* out = (float*)d_out;

    char* ws = (char*)d_ws;
    float*    acc  = (float*)ws;              // offset 0
    unsigned* maxk = (unsigned*)(ws + 128);   // 32 uints
    unsigned* mink = (unsigned*)(ws + 256);   // 32 uints

    hipMemsetAsync(ws, 0, 256, stream);          // acc = 0, maxk = 0
    hipMemsetAsync(ws + 256, 0xFF, 128, stream); // mink = 0xFFFFFFFF

    minmax_kernel<<<256, 256, 0, stream>>>((const float4*)img2, maxk, mink);
    ssim_kernel<<<NSTRIPS*NIMG, 64, 0, stream>>>(img1, img2, maxk, mink, acc);
    finalize_kernel<<<1, 1, 0, stream>>>(acc, out);
}